// Round 20
// baseline (6121.301 us; speedup 1.0000x reference)
//
#include <hip/hip_runtime.h>
#include <hip/hip_bf16.h>

#define M_TOTAL 131072
#define ATT_SCALE 0.17677669529663687f
#define LN_EPS 1e-5f
#define CDIV(a,b) (((a)+(b)-1)/(b))

using bf16x8 = __attribute__((ext_vector_type(8))) short;
using f32x4  = __attribute__((ext_vector_type(4))) float;

__device__ __forceinline__ float wredsum(float v){
#pragma unroll
  for (int m = 32; m; m >>= 1) v += __shfl_xor(v, m, 64);
  return v;
}

// fp32 -> bf16 (round-to-nearest-even) as raw bits
__device__ __forceinline__ unsigned short f2b(float x){
  union { float f; unsigned u; } v; v.f = x;
  unsigned r = v.u + 0x7FFFu + ((v.u >> 16) & 1u);
  return (unsigned short)(r >> 16);
}
__device__ __forceinline__ float b2f(unsigned short u){
  union { unsigned u32; float f; } v; v.u32 = (unsigned)u << 16; return v.f;
}

__global__ void zero1(float* p){ if (threadIdx.x == 0) *p = 0.f; }

// ---- one-time weight conversion: fp32 [K][N] -> bf16 transposed [N][K] ----
__global__ void convert_qkv(const float* __restrict__ Wk, const float* __restrict__ Wq,
                            const float* __restrict__ Wv, unsigned short* __restrict__ WrT){
  int idx = blockIdx.x * 256 + threadIdx.x;
  if (idx >= 8 * 768 * 256) return;
  int k = idx & 255;
  int n = (idx >> 8) % 768;
  int i = idx / (768 * 256);
  int sel = n >> 8, nn = n & 255, hh = nn >> 6, d = nn & 63;
  const float* W = sel == 0 ? Wk : sel == 1 ? Wq : Wv;
  WrT[idx] = f2b(W[((size_t)(i * 4 + hh) * 256 + k) * 64 + d]);
}

__global__ void convert_t(const float* __restrict__ in, unsigned short* __restrict__ outp,
                          int N, int K, int total){
  int idx = blockIdx.x * 256 + threadIdx.x;
  if (idx >= total) return;
  int k = idx % K;
  int n = (idx / K) % N;
  int i = idx / (K * N);
  outp[idx] = f2b(in[((size_t)i * K + k) * N + n]);
}

// lmW fp32 [256][65] -> lmWT bf16 [80][256] (rows 65..79 zero) ; lmb -> lmbp[80]
__global__ void convert_lmw(const float* __restrict__ lmW, const float* __restrict__ lmb,
                            unsigned short* __restrict__ lmWT, float* __restrict__ lmbp){
  int idx = blockIdx.x * 256 + threadIdx.x;
  if (idx >= 80 * 256) return;
  int k = idx & 255, c = idx >> 8;
  lmWT[idx] = (c < 65) ? f2b(lmW[k * 65 + c]) : (unsigned short)0;
  if (idx < 80) lmbp[idx] = (idx < 65) ? lmb[idx] : 0.f;
}

// ---- MFMA bf16 GEMM (m97 structure): C = A @ BT^T + bias, bf16 out ----
template<bool RELU>
__global__ __launch_bounds__(256)
void gemm_bf(const unsigned short* __restrict__ A, const unsigned short* __restrict__ BT,
             const float* __restrict__ bias, unsigned short* __restrict__ Cb,
             int N, int K){
  __shared__ __align__(16) unsigned short LDS[2][128][64];
  unsigned short (*As)[64] = LDS[0];
  unsigned short (*Bs)[64] = LDS[1];
  const int tid = threadIdx.x;
  const int rowBase = blockIdx.y * 128, colBase = blockIdx.x * 128;
  const int w = tid >> 6, lane = tid & 63;
  const int wm = w >> 1, wn = w & 1;
  const int lm = lane & 15, lk = lane >> 4;

  const int sgrow = w * 32 + (lane >> 3);
  const int sgcol = ((((lane & 7) * 16) ^ ((lane >> 3) << 4)) >> 1);
  const unsigned short* gA = A  + (size_t)(rowBase + sgrow) * K + sgcol;
  const unsigned short* gB = BT + (size_t)(colBase + sgrow) * K + sgcol;

  f32x4 acc[4][4];
#pragma unroll
  for (int m = 0; m < 4; ++m)
#pragma unroll
    for (int n = 0; n < 4; ++n) acc[m][n] = (f32x4){0.f, 0.f, 0.f, 0.f};

  for (int kt = 0; kt < K; kt += 64){
#pragma unroll
    for (int q = 0; q < 4; ++q){
      __builtin_amdgcn_global_load_lds(
        (const __attribute__((address_space(1))) void*)(gA + (size_t)(q * 8) * K + kt),
        (__attribute__((address_space(3))) void*)&As[w * 32 + q * 8][0], 16, 0, 0);
      __builtin_amdgcn_global_load_lds(
        (const __attribute__((address_space(1))) void*)(gB + (size_t)(q * 8) * K + kt),
        (__attribute__((address_space(3))) void*)&Bs[w * 32 + q * 8][0], 16, 0, 0);
    }
    __syncthreads();
#pragma unroll
    for (int half = 0; half < 2; ++half){
      const int cb = (half * 64 + lk * 16) ^ ((lm & 7) << 4);
      bf16x8 a[4], b[4];
#pragma unroll
      for (int m = 0; m < 4; ++m)
        a[m] = *(const bf16x8*)((const char*)&As[wm * 64 + m * 16 + lm][0] + cb);
#pragma unroll
      for (int n = 0; n < 4; ++n)
        b[n] = *(const bf16x8*)((const char*)&Bs[wn * 64 + n * 16 + lm][0] + cb);
#pragma unroll
      for (int m = 0; m < 4; ++m)
#pragma unroll
        for (int n = 0; n < 4; ++n)
          acc[m][n] = __builtin_amdgcn_mfma_f32_16x16x32_bf16(a[m], b[n], acc[m][n], 0, 0, 0);
    }
    __syncthreads();
  }

  // ---- epilogue: per-m LDS bounce -> full-line contiguous global stores ----
  unsigned short* bounce = &LDS[0][0][0] + w * 1152;   // wave-private [16][72]
  const int erow = lane >> 2;
  const int ecol = (lane & 3) * 16;
  const int gc = colBase + wn * 64 + ecol;
#pragma unroll
  for (int m = 0; m < 4; ++m){
#pragma unroll
    for (int n = 0; n < 4; ++n){
      int c = colBase + wn * 64 + n * 16 + lm;
      float bv = bias ? bias[c] : 0.f;
#pragma unroll
      for (int i = 0; i < 4; ++i){
        float v = acc[m][n][i] + bv;
        if (RELU) v = fmaxf(v, 0.f);
        bounce[(lk * 4 + i) * 72 + n * 16 + lm] = f2b(v);
      }
    }
    asm volatile("s_waitcnt lgkmcnt(0)" ::: "memory");
    uint4 v0 = *(const uint4*)&bounce[erow * 72 + ecol];
    uint4 v1 = *(const uint4*)&bounce[erow * 72 + ecol + 8];
    size_t go = (size_t)(rowBase + wm * 64 + m * 16 + erow) * N + gc;
    *(uint4*)(Cb + go)     = v0;
    *(uint4*)(Cb + go + 8) = v1;
  }
}

// ---- fused GEMM (N=256) + bias + residual + LayerNorm -> h_bf (round-9 verified) ----
// 128x256 tile per block, 512 threads = 8 waves (2 wm x 4 wn). BK=64.
__global__ __launch_bounds__(512)
void gemm_ln(const unsigned short* __restrict__ A, const unsigned short* __restrict__ BT,
             const float* __restrict__ bias, unsigned short* __restrict__ h_bf,
             const float* __restrict__ g, const float* __restrict__ b, int K){
  __shared__ unsigned short As[128][72];
  __shared__ unsigned short Bs[256][72];
  __shared__ float redA[4][128];
  __shared__ float redB[4][128];
  const int tid = threadIdx.x;
  const int rowBase = blockIdx.x * 128;
  const int w = tid >> 6, lane = tid & 63;
  const int wm = w >> 2, wn = w & 3;
  const int lm = lane & 15, lk = lane >> 4;
  const int srow = tid >> 3, scol = (tid & 7) * 8;

  f32x4 acc[4][4];
#pragma unroll
  for (int m = 0; m < 4; ++m)
#pragma unroll
    for (int n = 0; n < 4; ++n) acc[m][n] = (f32x4){0.f, 0.f, 0.f, 0.f};

  for (int kt = 0; kt < K; kt += 64){
#pragma unroll
    for (int q = 0; q < 2; ++q){
      int r = srow + 64 * q;
      *(uint4*)&As[r][scol] = *(const uint4*)(A + (size_t)(rowBase + r) * K + kt + scol);
    }
#pragma unroll
    for (int q = 0; q < 4; ++q){
      int r = srow + 64 * q;
      *(uint4*)&Bs[r][scol] = *(const uint4*)(BT + (size_t)r * K + kt + scol);
    }
    __syncthreads();
#pragma unroll
    for (int half = 0; half < 2; ++half){
      bf16x8 a[4], b8[4];
#pragma unroll
      for (int m = 0; m < 4; ++m)
        a[m] = *(const bf16x8*)&As[wm * 64 + m * 16 + lm][half * 32 + lk * 8];
#pragma unroll
      for (int n = 0; n < 4; ++n)
        b8[n] = *(const bf16x8*)&Bs[wn * 64 + n * 16 + lm][half * 32 + lk * 8];
#pragma unroll
      for (int m = 0; m < 4; ++m)
#pragma unroll
        for (int n = 0; n < 4; ++n)
          acc[m][n] = __builtin_amdgcn_mfma_f32_16x16x32_bf16(a[m], b8[n], acc[m][n], 0, 0, 0);
    }
    __syncthreads();
  }

  // x = acc + bias + residual(h_bf), in place
  float gg[4], bb[4], bv[4];
#pragma unroll
  for (int n = 0; n < 4; ++n){
    int c = wn * 64 + n * 16 + lm;
    bv[n] = bias[c]; gg[n] = g[c]; bb[n] = b[c];
  }
#pragma unroll
  for (int m = 0; m < 4; ++m)
#pragma unroll
    for (int i = 0; i < 4; ++i){
      size_t rr = (size_t)(rowBase + wm * 64 + m * 16 + lk * 4 + i) * 256;
#pragma unroll
      for (int n = 0; n < 4; ++n)
        acc[m][n][i] += bv[n] + b2f(h_bf[rr + wn * 64 + n * 16 + lm]);
    }

  // mean: per-thread 4-col partials -> 16-lane tree -> cross-wave LDS
  float pr[4][4];
#pragma unroll
  for (int m = 0; m < 4; ++m)
#pragma unroll
    for (int i = 0; i < 4; ++i)
      pr[m][i] = acc[m][0][i] + acc[m][1][i] + acc[m][2][i] + acc[m][3][i];
#pragma unroll
  for (int mask = 1; mask < 16; mask <<= 1)
#pragma unroll
    for (int m = 0; m < 4; ++m)
#pragma unroll
      for (int i = 0; i < 4; ++i)
        pr[m][i] += __shfl_xor(pr[m][i], mask, 64);
  if (lm == 0){
#pragma unroll
    for (int m = 0; m < 4; ++m)
#pragma unroll
      for (int i = 0; i < 4; ++i)
        redA[wn][wm * 64 + m * 16 + lk * 4 + i] = pr[m][i];
  }
  __syncthreads();
  float mean[4][4];
#pragma unroll
  for (int m = 0; m < 4; ++m)
#pragma unroll
    for (int i = 0; i < 4; ++i){
      int lr = wm * 64 + m * 16 + lk * 4 + i;
      mean[m][i] = (redA[0][lr] + redA[1][lr] + redA[2][lr] + redA[3][lr]) * (1.f / 256.f);
    }

  // variance
#pragma unroll
  for (int m = 0; m < 4; ++m)
#pragma unroll
    for (int i = 0; i < 4; ++i){
      float q = 0.f;
#pragma unroll
      for (int n = 0; n < 4; ++n){
        float d = acc[m][n][i] - mean[m][i];
        q += d * d;
      }
      pr[m][i] = q;
    }
#pragma unroll
  for (int mask = 1; mask < 16; mask <<= 1)
#pragma unroll
    for (int m = 0; m < 4; ++m)
#pragma unroll
      for (int i = 0; i < 4; ++i)
        pr[m][i] += __shfl_xor(pr[m][i], mask, 64);
  if (lm == 0){
#pragma unroll
    for (int m = 0; m < 4; ++m)
#pragma unroll
      for (int i = 0; i < 4; ++i)
        redB[wn][wm * 64 + m * 16 + lk * 4 + i] = pr[m][i];
  }
  __syncthreads();

#pragma unroll
  for (int m = 0; m < 4; ++m)
#pragma unroll
    for (int i = 0; i < 4; ++i){
      int lr = wm * 64 + m * 16 + lk * 4 + i;
      float var = (redB[0][lr] + redB[1][lr] + redB[2][lr] + redB[3][lr]) * (1.f / 256.f);
      float rstd = rsqrtf(var + LN_EPS);
      size_t rr = (size_t)(rowBase + lr) * 256;
#pragma unroll
      for (int n = 0; n < 4; ++n){
        int c = wn * 64 + n * 16 + lm;
        float nv = (acc[m][n][i] - mean[m][i]) * rstd * gg[n] + bb[n];
        h_bf[rr + c] = f2b(nv);
      }
    }
}

// h_bf[r][c] = bf16(tok[x[m]][c] + pos[x[m]][c])  (pos indexed by TOKEN ids -- source bug)
__global__ void embed_kernel(const int* __restrict__ x, const float* __restrict__ tok,
                             const float* __restrict__ pos, unsigned short* __restrict__ h_bf,
                             int row0, int nrows){
  int total = nrows * 64;
  for (int idx = blockIdx.x * blockDim.x + threadIdx.x; idx < total; idx += gridDim.x * blockDim.x){
    int r = idx >> 6, c4 = (idx & 63) * 4;
    int t = x[row0 + r];
    float4 tv = *(const float4*)(tok + t * 256 + c4);
    float4 pv = *(const float4*)(pos + t * 256 + c4);
    ushort4 o;
    o.x = f2b(tv.x + pv.x); o.y = f2b(tv.y + pv.y);
    o.z = f2b(tv.z + pv.z); o.w = f2b(tv.w + pv.w);
    *(ushort4*)(h_bf + (size_t)r * 256 + c4) = o;
  }
}

// ---- MFMA fused attention: one block per sequence, 4 waves = 4 heads ----
__global__ __launch_bounds__(256)
void attn_mfma(const unsigned short* __restrict__ kqv, unsigned short* __restrict__ attn){
  __shared__ __align__(16) unsigned short VT[4][64 * 40];
  __shared__ __align__(16) unsigned short PH[4][32 * 40];
  const int ls = blockIdx.x;
  const int tid = threadIdx.x;
  const int hd = tid >> 6, lane = tid & 63;
  const int lm = lane & 15, lk = lane >> 4;

#pragma unroll
  for (int it = 0; it < 4; ++it){
    int idx = it * 256 + tid;
    int row = idx & 31, col = (idx >> 5) * 8;
    int hh = col >> 6, d = col & 63;
    union { uint4 v4; unsigned short s[8]; } u;
    u.v4 = *(const uint4*)(kqv + (size_t)(ls * 32 + row) * 768 + 512 + col);
#pragma unroll
    for (int j = 0; j < 8; ++j)
      VT[hh][(d + j) * 40 + row] = u.s[j];
  }
  __syncthreads();

  const unsigned short* Kg = kqv + (size_t)(ls * 32) * 768 + hd * 64;
  const unsigned short* Qg = Kg + 256;
  f32x4 sacc[2][2];
#pragma unroll
  for (int m = 0; m < 2; ++m)
#pragma unroll
    for (int n = 0; n < 2; ++n) sacc[m][n] = (f32x4){0.f, 0.f, 0.f, 0.f};
#pragma unroll
  for (int kk = 0; kk < 2; ++kk){
    bf16x8 a[2], b[2];
#pragma unroll
    for (int m = 0; m < 2; ++m)
      a[m] = *(const bf16x8*)(Kg + (size_t)(m * 16 + lm) * 768 + kk * 32 + lk * 8);
#pragma unroll
    for (int n = 0; n < 2; ++n)
      b[n] = *(const bf16x8*)(Qg + (size_t)(n * 16 + lm) * 768 + kk * 32 + lk * 8);
#pragma unroll
    for (int m = 0; m < 2; ++m)
#pragma unroll
      for (int n = 0; n < 2; ++n)
        sacc[m][n] = __builtin_amdgcn_mfma_f32_16x16x32_bf16(a[m], b[n], sacc[m][n], 0, 0, 0);
  }

#pragma unroll
  for (int m = 0; m < 2; ++m){
#pragma unroll
    for (int i = 0; i < 4; ++i){
      int t = m * 16 + lk * 4 + i;
      float v0 = sacc[m][0][i] * ATT_SCALE;
      float v1 = sacc[m][1][i] * ATT_SCALE;
      bool m0 = (lm <= t), m1 = (16 + lm <= t);
      float mx = fmaxf(m0 ? v0 : -1e30f, m1 ? v1 : -1e30f);
#pragma unroll
      for (int msk = 1; msk < 16; msk <<= 1) mx = fmaxf(mx, __shfl_xor(mx, msk, 64));
      float e0 = m0 ? expf(v0 - mx) : 0.f;
      float e1 = m1 ? expf(v1 - mx) : 0.f;
      float sm = e0 + e1;
#pragma unroll
      for (int msk = 1; msk < 16; msk <<= 1) sm += __shfl_xor(sm, msk, 64);
      float inv = 1.f / sm;
      PH[hd][t * 40 + lm]      = f2b(e0 * inv);
      PH[hd][t * 40 + 16 + lm] = f2b(e1 * inv);
    }
  }
  __syncthreads();

  f32x4 pacc[2][4];
  {
    bf16x8 a[2], b[4];
#pragma unroll
    for (int m = 0; m < 2; ++m)
      a[m] = *(const bf16x8*)&PH[hd][(m * 16 + lm) * 40 + lk * 8];
#pragma unroll
    for (int n = 0; n < 4; ++n)
      b[n] = *(const bf16x8*)&VT[hd][(n * 16 + lm) * 40 + lk * 8];
#pragma unroll
    for (int m = 0; m < 2; ++m)
#pragma unroll
      for (int n = 0; n < 4; ++n)
        pacc[m][n] = __builtin_amdgcn_mfma_f32_16x16x32_bf16(
            a[m], b[n], (f32x4){0.f, 0.f, 0.f, 0.f}, 0, 0, 0);
  }

  unsigned short* bounce = &VT[hd][0];
#pragma unroll
  for (int m = 0; m < 2; ++m)
#pragma unroll
    for (int n = 0; n < 4; ++n)
#pragma unroll
      for (int i = 0; i < 4; ++i)
        bounce[(m * 16 + lk * 4 + i) * 72 + n * 16 + lm] = f2b(pacc[m][n][i]);
  asm volatile("s_waitcnt lgkmcnt(0)" ::: "memory");
  const int er = lane >> 1, ec = (lane & 1) * 32;
  size_t gbase = (size_t)(ls * 32 + er) * 256 + hd * 64 + ec;
#pragma unroll
  for (int j = 0; j < 4; ++j)
    *(uint4*)(attn + gbase + j * 8) = *(const uint4*)&bounce[er * 72 + ec + j * 8];
}

// ---- fused logits (MFMA) + log-softmax + NLL ----
__global__ __launch_bounds__(256)
void logits_loss_mfma(const unsigned short* __restrict__ h_bf,
                      const unsigned short* __restrict__ lmWT,
                      const float* __restrict__ lmbp, const int* __restrict__ y,
                      float* __restrict__ out, float* __restrict__ partial,
                      int row0){
  __shared__ unsigned short As[64][136];
  __shared__ unsigned short Ws[80][136];
  __shared__ float redw[4];
  const int tid = threadIdx.x;
  const int rowBase = blockIdx.x * 64;
  const int w = tid >> 6, lane = tid & 63;
  const int lm = lane & 15, lk = lane >> 4;

  f32x4 acc[5];
#pragma unroll
  for (int n = 0; n < 5; ++n) acc[n] = (f32x4){0.f, 0.f, 0.f, 0.f};

  for (int kt = 0; kt < 256; kt += 128){
#pragma unroll
    for (int q = 0; q < 4; ++q){
      int idx = tid + 256 * q;
      int r = idx >> 4, k8 = (idx & 15) * 8;
      *(uint4*)&As[r][k8] = *(const uint4*)(h_bf + (size_t)(rowBase + r) * 256 + kt + k8);
    }
#pragma unroll
    for (int q = 0; q < 5; ++q){
      int idx = tid + 256 * q;
      int r = idx >> 4, k8 = (idx & 15) * 8;
      *(uint4*)&Ws[r][k8] = *(const uint4*)(lmWT + (size_t)r * 256 + kt + k8);
    }
    __syncthreads();
#pragma unroll
    for (int kc = 0; kc < 4; ++kc){
      bf16x8 a = *(const bf16x8*)&As[w * 16 + lm][kc * 32 + lk * 8];
#pragma unroll
      for (int n = 0; n < 5; ++n){
        bf16x8 bb = *(const bf16x8*)&Ws[n * 16 + lm][kc * 32 + lk * 8];
        acc[n] = __builtin_amdgcn_mfma_f32_16x16x32_bf16(a, bb, acc[n], 0, 0, 0);
      }
    }
    __syncthreads();
  }

#pragma unroll
  for (int n = 0; n < 5; ++n){
    int c = n * 16 + lm;
    float bv = lmbp[c];
#pragma unroll
    for (int i = 0; i < 4; ++i){
      acc[n][i] += bv;
      if (c < 65){
        int r = rowBase + w * 16 + lk * 4 + i;
        out[(size_t)(row0 + r) * 65 + c] = acc[n][i];
      }
    }
  }

  float nll = 0.f;
#pragma unroll
  for (int i = 0; i < 4; ++i){
    float mx = -1e30f;
#pragma unroll
    for (int n = 0; n < 5; ++n)
      if (n * 16 + lm < 65) mx = fmaxf(mx, acc[n][i]);
#pragma unroll
    for (int mask = 1; mask < 16; mask <<= 1) mx = fmaxf(mx, __shfl_xor(mx, mask, 64));
    float se = 0.f;
#pragma unroll
    for (int n = 0; n < 5; ++n)
      if (n * 16 + lm < 65) se += expf(acc[n][i] - mx);
#pragma unroll
    for (int mask = 1; mask < 16; mask <<= 1) se += __shfl_xor(se, mask, 64);
    float lse = mx + logf(se);
    int gr = rowBase + w * 16 + lk * 4 + i;
    int yv = y[row0 + gr];
    float ly = 0.f;
#pragma unroll
    for (int n = 0; n < 5; ++n)
      if (n * 16 + lm == yv) ly = acc[n][i];
#pragma unroll
    for (int mask = 1; mask < 16; mask <<= 1) ly += __shfl_xor(ly, mask, 64);
    nll += lse - ly;
  }
  if (lm != 0) nll = 0.f;
  nll += __shfl_xor(nll, 16, 64);
  nll += __shfl_xor(nll, 32, 64);
  if (lane == 0) redw[w] = nll;
  __syncthreads();
  if (tid == 0) partial[blockIdx.x] = redw[0] + redw[1] + redw[2] + redw[3];
}

__global__ __launch_bounds__(256)
void loss_red(const float* __restrict__ partial, int n, float* __restrict__ loss_sum){
  __shared__ float red[256];
  float s = 0.f;
  for (int i = threadIdx.x; i < n; i += 256) s += partial[i];
  red[threadIdx.x] = s;
  __syncthreads();
  for (int st = 128; st; st >>= 1){
    if (threadIdx.x < st) red[threadIdx.x] += red[threadIdx.x + st];
    __syncthreads();
  }
  if (threadIdx.x == 0) *loss_sum += red[0];
}

__global__ void loss_fin(const float* __restrict__ loss_sum, float* __restrict__ out){
  if (threadIdx.x == 0)
    out[(size_t)M_TOTAL * 65] = *loss_sum * (1.f / (float)M_TOTAL);
}

extern "C" void kernel_launch(void* const* d_in, const int* in_sizes, int n_in,
                              void* d_out, int out_size, void* d_ws, size_t ws_size,
                              hipStream_t stream) {
  const int*   x    = (const int*)  d_in[0];
  const int*   y    = (const int*)  d_in[1];
  const float* tok  = (const float*)d_in[2];
  const float* pos  = (const float*)d_in[3];
  const float* Wk   = (const float*)d_in[4];
  const float* Wq   = (const float*)d_in[5];
  const float* Wv   = (const float*)d_in[6];
  const float* Wp   = (const float*)d_in[7];
  const float* bp   = (const float*)d_in[8];
  const float* ln1g = (const float*)d_in[9];
  const float* ln1b = (const float*)d_in[10];
  const float* W1   = (const float*)d_in[11];
  const float* b1   = (const float*)d_in[12];
  const float* W2   = (const float*)d_in[13];
  const float* b2   = (const float*)d_in[14];
  const float* ln2g = (const float*)d_in[15];
  const float* ln2b = (const float*)d_in[16];
  const float* lmW  = (const float*)d_in[17];
  const float* lmb  = (const float*)d_in[18];
  float* out = (float*)d_out;

  // ws layout: loss_sum[64] | partial[1024] | lmWT+lmbp | bf16 weights | per-row buffers
  float* loss_sum = (float*)d_ws;
  float* partial  = loss_sum + 64;
  unsigned short* lmWT = (unsigned short*)(partial + 1024);      // [80][256]
  float* lmbp = (float*)(lmWT + 80 * 256);                       // [80]
  unsigned short* WrT = (unsigned short*)(lmbp + 80);            // [8][768][256]
  unsigned short* WpT = WrT + (size_t)8 * 768 * 256;             // [8][256][256]
  unsigned short* W1T = WpT + (size_t)8 * 256 * 256;             // [8][1024][256]
  unsigned short* W2T = W1T + (size_t)8 * 1024 * 256;            // [8][256][1024]
  unsigned short* bufs = W2T + (size_t)8 * 256 * 1024;
  size_t fixed = (size_t)(64 + 1024) * 4 + (size_t)80 * 256 * 2 + 80 * 4 +
                 ((size_t)8 * 768 * 256 + 8 * 256 * 256 + 8 * 1024 * 256 + 8 * 256 * 1024) * 2;
  // per-row (all bf16): kqv768 + h_bf256 + attn256 + ff1 1024
  const size_t per_row = (size_t)(768 + 256 + 256 + 1024) * 2;
  size_t avail = ws_size > fixed ? ws_size - fixed : 0;
  long rmax = (long)(avail / per_row) & ~255L;
  if (rmax < 256) rmax = 256;
  int R = (int)(rmax < (long)M_TOTAL ? rmax : (long)M_TOTAL);

  unsigned short* kqv_b  = bufs;                       // [R][768] bf16
  unsigned short* h_bf   = kqv_b  + (size_t)R * 768;   // [R][256] bf16 (residual stream)
  unsigned short* attn_b = h_bf   + (size_t)R * 256;   // [R][256] bf16
  unsigned short* ff1_b  = attn_b + (size_t)R * 256;   // [R][1024] bf16

  zero1<<<1, 64, 0, stream>>>(loss_sum);
  convert_qkv<<<CDIV(8 * 768 * 256, 256), 256, 0, stream>>>(Wk, Wq, Wv, WrT);
  convert_t<<<CDIV(8 * 256 * 256, 256), 256, 0, stream>>>(Wp, WpT, 256, 256, 8 * 256 * 256);
  convert_t<<<CDIV(8 * 1024 * 256, 256), 256, 0, stream>>>(W1, W1T, 1024, 256, 8 * 1024 * 256);
  convert_t<<<CDIV(8 * 256 * 1024, 256), 256, 0, stream>>>(W2, W2T, 256, 1024, 8 * 256 * 1024);
  convert_lmw<<<80, 256, 0, stream>>>(lmW, lmb, lmWT, lmbp);

  for (int row0 = 0; row0 < M_TOTAL; row0 += R){
    int nr = (M_TOTAL - row0) < R ? (M_TOTAL - row0) : R;
    int eg = CDIV(nr * 64, 256); if (eg > 4096) eg = 4096;
    embed_kernel<<<eg, 256, 0, stream>>>(x, tok, pos, h_bf, row0, nr);
    for (int i = 0; i < 8; ++i){
      gemm_bf<false><<<dim3(6, nr / 128), 256, 0, stream>>>(
          h_bf, WrT + (size_t)i * 768 * 256, nullptr, kqv_b, 768, 256);
      attn_mfma<<<nr / 32, 256, 0, stream>>>(kqv_b, attn_b);
      gemm_ln<<<nr / 128, 512, 0, stream>>>(
          attn_b, WpT + (size_t)i * 256 * 256, bp + i * 256, h_bf,
          ln1g + i * 256, ln1b + i * 256, 256);
      gemm_bf<true><<<dim3(8, nr / 128), 256, 0, stream>>>(
          h_bf, W1T + (size_t)i * 1024 * 256, b1 + i * 1024, ff1_b, 1024, 256);
      gemm_ln<<<nr / 128, 512, 0, stream>>>(
          ff1_b, W2T + (size_t)i * 256 * 1024, b2 + i * 256, h_bf,
          ln2g + i * 256, ln2b + i * 256, 1024);
    }
    logits_loss_mfma<<<nr / 64, 256, 0, stream>>>(h_bf, lmWT, lmbp, y, out, partial, row0);
    loss_red<<<1, 256, 0, stream>>>(partial, nr / 64, loss_sum);
  }
  loss_fin<<<1, 64, 0, stream>>>(loss_sum, out);
}

// Round 21
// 5459.182 us; speedup vs baseline: 1.1213x; 1.1213x over previous
//
#include <hip/hip_runtime.h>
#include <hip/hip_bf16.h>

#define M_TOTAL 131072
#define ATT_SCALE 0.17677669529663687f
#define LN_EPS 1e-5f
#define CDIV(a,b) (((a)+(b)-1)/(b))

using bf16x8 = __attribute__((ext_vector_type(8))) short;
using f32x4  = __attribute__((ext_vector_type(4))) float;

__device__ __forceinline__ float wredsum(float v){
#pragma unroll
  for (int m = 32; m; m >>= 1) v += __shfl_xor(v, m, 64);
  return v;
}

// fp32 -> bf16 (round-to-nearest-even) as raw bits
__device__ __forceinline__ unsigned short f2b(float x){
  union { float f; unsigned u; } v; v.f = x;
  unsigned r = v.u + 0x7FFFu + ((v.u >> 16) & 1u);
  return (unsigned short)(r >> 16);
}
__device__ __forceinline__ float b2f(unsigned short u){
  union { unsigned u32; float f; } v; v.u32 = (unsigned)u << 16; return v.f;
}

__global__ void zero1(float* p){ if (threadIdx.x == 0) *p = 0.f; }

// ---- one-time weight conversion: fp32 [K][N] -> bf16 transposed [N][K] ----
__global__ void convert_qkv(const float* __restrict__ Wk, const float* __restrict__ Wq,
                            const float* __restrict__ Wv, unsigned short* __restrict__ WrT){
  int idx = blockIdx.x * 256 + threadIdx.x;
  if (idx >= 8 * 768 * 256) return;
  int k = idx & 255;
  int n = (idx >> 8) % 768;
  int i = idx / (768 * 256);
  int sel = n >> 8, nn = n & 255, hh = nn >> 6, d = nn & 63;
  const float* W = sel == 0 ? Wk : sel == 1 ? Wq : Wv;
  WrT[idx] = f2b(W[((size_t)(i * 4 + hh) * 256 + k) * 64 + d]);
}

__global__ void convert_t(const float* __restrict__ in, unsigned short* __restrict__ outp,
                          int N, int K, int total){
  int idx = blockIdx.x * 256 + threadIdx.x;
  if (idx >= total) return;
  int k = idx % K;
  int n = (idx / K) % N;
  int i = idx / (K * N);
  outp[idx] = f2b(in[((size_t)i * K + k) * N + n]);
}

// lmW fp32 [256][65] -> lmWT bf16 [80][256] (rows 65..79 zero) ; lmb -> lmbp[80]
__global__ void convert_lmw(const float* __restrict__ lmW, const float* __restrict__ lmb,
                            unsigned short* __restrict__ lmWT, float* __restrict__ lmbp){
  int idx = blockIdx.x * 256 + threadIdx.x;
  if (idx >= 80 * 256) return;
  int k = idx & 255, c = idx >> 8;
  lmWT[idx] = (c < 65) ? f2b(lmW[k * 65 + c]) : (unsigned short)0;
  if (idx < 80) lmbp[idx] = (idx < 65) ? lmb[idx] : 0.f;
}

// ---- MFMA bf16 GEMM (m97 structure): C = A @ BT^T + bias, bf16 out ----
template<bool RELU>
__global__ __launch_bounds__(256)
void gemm_bf(const unsigned short* __restrict__ A, const unsigned short* __restrict__ BT,
             const float* __restrict__ bias, unsigned short* __restrict__ Cb,
             int N, int K){
  __shared__ __align__(16) unsigned short LDS[2][128][64];
  unsigned short (*As)[64] = LDS[0];
  unsigned short (*Bs)[64] = LDS[1];
  const int tid = threadIdx.x;
  const int rowBase = blockIdx.y * 128, colBase = blockIdx.x * 128;
  const int w = tid >> 6, lane = tid & 63;
  const int wm = w >> 1, wn = w & 1;
  const int lm = lane & 15, lk = lane >> 4;

  const int sgrow = w * 32 + (lane >> 3);
  const int sgcol = ((((lane & 7) * 16) ^ ((lane >> 3) << 4)) >> 1);
  const unsigned short* gA = A  + (size_t)(rowBase + sgrow) * K + sgcol;
  const unsigned short* gB = BT + (size_t)(colBase + sgrow) * K + sgcol;

  f32x4 acc[4][4];
#pragma unroll
  for (int m = 0; m < 4; ++m)
#pragma unroll
    for (int n = 0; n < 4; ++n) acc[m][n] = (f32x4){0.f, 0.f, 0.f, 0.f};

  for (int kt = 0; kt < K; kt += 64){
#pragma unroll
    for (int q = 0; q < 4; ++q){
      __builtin_amdgcn_global_load_lds(
        (const __attribute__((address_space(1))) void*)(gA + (size_t)(q * 8) * K + kt),
        (__attribute__((address_space(3))) void*)&As[w * 32 + q * 8][0], 16, 0, 0);
      __builtin_amdgcn_global_load_lds(
        (const __attribute__((address_space(1))) void*)(gB + (size_t)(q * 8) * K + kt),
        (__attribute__((address_space(3))) void*)&Bs[w * 32 + q * 8][0], 16, 0, 0);
    }
    __syncthreads();
#pragma unroll
    for (int half = 0; half < 2; ++half){
      const int cb = (half * 64 + lk * 16) ^ ((lm & 7) << 4);
      bf16x8 a[4], b[4];
#pragma unroll
      for (int m = 0; m < 4; ++m)
        a[m] = *(const bf16x8*)((const char*)&As[wm * 64 + m * 16 + lm][0] + cb);
#pragma unroll
      for (int n = 0; n < 4; ++n)
        b[n] = *(const bf16x8*)((const char*)&Bs[wn * 64 + n * 16 + lm][0] + cb);
#pragma unroll
      for (int m = 0; m < 4; ++m)
#pragma unroll
        for (int n = 0; n < 4; ++n)
          acc[m][n] = __builtin_amdgcn_mfma_f32_16x16x32_bf16(a[m], b[n], acc[m][n], 0, 0, 0);
    }
    __syncthreads();
  }

  // ---- epilogue: per-m LDS bounce -> full-line contiguous global stores ----
  unsigned short* bounce = &LDS[0][0][0] + w * 1152;   // wave-private [16][72]
  const int erow = lane >> 2;
  const int ecol = (lane & 3) * 16;
  const int gc = colBase + wn * 64 + ecol;
#pragma unroll
  for (int m = 0; m < 4; ++m){
#pragma unroll
    for (int n = 0; n < 4; ++n){
      int c = colBase + wn * 64 + n * 16 + lm;
      float bv = bias ? bias[c] : 0.f;
#pragma unroll
      for (int i = 0; i < 4; ++i){
        float v = acc[m][n][i] + bv;
        if (RELU) v = fmaxf(v, 0.f);
        bounce[(lk * 4 + i) * 72 + n * 16 + lm] = f2b(v);
      }
    }
    asm volatile("s_waitcnt lgkmcnt(0)" ::: "memory");
    uint4 v0 = *(const uint4*)&bounce[erow * 72 + ecol];
    uint4 v1 = *(const uint4*)&bounce[erow * 72 + ecol + 8];
    size_t go = (size_t)(rowBase + wm * 64 + m * 16 + erow) * N + gc;
    *(uint4*)(Cb + go)     = v0;
    *(uint4*)(Cb + go + 8) = v1;
  }
}

// ---- fused GEMM (N=256) + bias + residual + LayerNorm -> h_bf ----
// 128x256 tile, 512 threads = 8 waves (2 wm x 4 wn), BK=64.
// Staging ported verbatim from gemm_bf: global_load_lds + XOR swizzle, linear LDS.
__global__ __launch_bounds__(512)
void gemm_ln(const unsigned short* __restrict__ A, const unsigned short* __restrict__ BT,
             const float* __restrict__ bias, unsigned short* __restrict__ h_bf,
             const float* __restrict__ g, const float* __restrict__ b, int K){
  __shared__ __align__(16) unsigned short As[128][64];
  __shared__ __align__(16) unsigned short Bs[256][64];
  __shared__ float redA[4][128];
  __shared__ float redB[4][128];
  const int tid = threadIdx.x;
  const int rowBase = blockIdx.x * 128;
  const int w = tid >> 6, lane = tid & 63;
  const int wm = w >> 2, wn = w & 3;
  const int lm = lane & 15, lk = lane >> 4;

  // staging: 8-row groups; row&7 == lane>>3 for every issue
  const int sgcol = ((((lane & 7) * 16) ^ ((lane >> 3) << 4)) >> 1);
  const unsigned short* gA = A  + (size_t)(rowBase + w * 16 + (lane >> 3)) * K + sgcol;
  const unsigned short* gB = BT + (size_t)(w * 32 + (lane >> 3)) * K + sgcol;

  f32x4 acc[4][4];
#pragma unroll
  for (int m = 0; m < 4; ++m)
#pragma unroll
    for (int n = 0; n < 4; ++n) acc[m][n] = (f32x4){0.f, 0.f, 0.f, 0.f};

  for (int kt = 0; kt < K; kt += 64){
#pragma unroll
    for (int q = 0; q < 2; ++q)
      __builtin_amdgcn_global_load_lds(
        (const __attribute__((address_space(1))) void*)(gA + (size_t)(q * 8) * K + kt),
        (__attribute__((address_space(3))) void*)&As[w * 16 + q * 8][0], 16, 0, 0);
#pragma unroll
    for (int q = 0; q < 4; ++q)
      __builtin_amdgcn_global_load_lds(
        (const __attribute__((address_space(1))) void*)(gB + (size_t)(q * 8) * K + kt),
        (__attribute__((address_space(3))) void*)&Bs[w * 32 + q * 8][0], 16, 0, 0);
    __syncthreads();
#pragma unroll
    for (int half = 0; half < 2; ++half){
      const int cb = (half * 64 + lk * 16) ^ ((lm & 7) << 4);
      bf16x8 a[4], b8[4];
#pragma unroll
      for (int m = 0; m < 4; ++m)
        a[m] = *(const bf16x8*)((const char*)&As[wm * 64 + m * 16 + lm][0] + cb);
#pragma unroll
      for (int n = 0; n < 4; ++n)
        b8[n] = *(const bf16x8*)((const char*)&Bs[wn * 64 + n * 16 + lm][0] + cb);
#pragma unroll
      for (int m = 0; m < 4; ++m)
#pragma unroll
        for (int n = 0; n < 4; ++n)
          acc[m][n] = __builtin_amdgcn_mfma_f32_16x16x32_bf16(a[m], b8[n], acc[m][n], 0, 0, 0);
    }
    __syncthreads();
  }

  // x = acc + bias + residual(h_bf), in place
  float gg[4], bb[4], bv[4];
#pragma unroll
  for (int n = 0; n < 4; ++n){
    int c = wn * 64 + n * 16 + lm;
    bv[n] = bias[c]; gg[n] = g[c]; bb[n] = b[c];
  }
#pragma unroll
  for (int m = 0; m < 4; ++m)
#pragma unroll
    for (int i = 0; i < 4; ++i){
      size_t rr = (size_t)(rowBase + wm * 64 + m * 16 + lk * 4 + i) * 256;
#pragma unroll
      for (int n = 0; n < 4; ++n)
        acc[m][n][i] += bv[n] + b2f(h_bf[rr + wn * 64 + n * 16 + lm]);
    }

  // mean: per-thread 4-col partials -> 16-lane tree -> cross-wave LDS
  float pr[4][4];
#pragma unroll
  for (int m = 0; m < 4; ++m)
#pragma unroll
    for (int i = 0; i < 4; ++i)
      pr[m][i] = acc[m][0][i] + acc[m][1][i] + acc[m][2][i] + acc[m][3][i];
#pragma unroll
  for (int mask = 1; mask < 16; mask <<= 1)
#pragma unroll
    for (int m = 0; m < 4; ++m)
#pragma unroll
      for (int i = 0; i < 4; ++i)
        pr[m][i] += __shfl_xor(pr[m][i], mask, 64);
  if (lm == 0){
#pragma unroll
    for (int m = 0; m < 4; ++m)
#pragma unroll
      for (int i = 0; i < 4; ++i)
        redA[wn][wm * 64 + m * 16 + lk * 4 + i] = pr[m][i];
  }
  __syncthreads();
  float mean[4][4];
#pragma unroll
  for (int m = 0; m < 4; ++m)
#pragma unroll
    for (int i = 0; i < 4; ++i){
      int lr = wm * 64 + m * 16 + lk * 4 + i;
      mean[m][i] = (redA[0][lr] + redA[1][lr] + redA[2][lr] + redA[3][lr]) * (1.f / 256.f);
    }

  // variance
#pragma unroll
  for (int m = 0; m < 4; ++m)
#pragma unroll
    for (int i = 0; i < 4; ++i){
      float q = 0.f;
#pragma unroll
      for (int n = 0; n < 4; ++n){
        float d = acc[m][n][i] - mean[m][i];
        q += d * d;
      }
      pr[m][i] = q;
    }
#pragma unroll
  for (int mask = 1; mask < 16; mask <<= 1)
#pragma unroll
    for (int m = 0; m < 4; ++m)
#pragma unroll
      for (int i = 0; i < 4; ++i)
        pr[m][i] += __shfl_xor(pr[m][i], mask, 64);
  if (lm == 0){
#pragma unroll
    for (int m = 0; m < 4; ++m)
#pragma unroll
      for (int i = 0; i < 4; ++i)
        redB[wn][wm * 64 + m * 16 + lk * 4 + i] = pr[m][i];
  }
  __syncthreads();

#pragma unroll
  for (int m = 0; m < 4; ++m)
#pragma unroll
    for (int i = 0; i < 4; ++i){
      int lr = wm * 64 + m * 16 + lk * 4 + i;
      float var = (redB[0][lr] + redB[1][lr] + redB[2][lr] + redB[3][lr]) * (1.f / 256.f);
      float rstd = rsqrtf(var + LN_EPS);
      size_t rr = (size_t)(rowBase + lr) * 256;
#pragma unroll
      for (int n = 0; n < 4; ++n){
        int c = wn * 64 + n * 16 + lm;
        float nv = (acc[m][n][i] - mean[m][i]) * rstd * gg[n] + bb[n];
        h_bf[rr + c] = f2b(nv);
      }
    }
}

// h_bf[r][c] = bf16(tok[x[m]][c] + pos[x[m]][c])  (pos indexed by TOKEN ids -- source bug)
__global__ void embed_kernel(const int* __restrict__ x, const float* __restrict__ tok,
                             const float* __restrict__ pos, unsigned short* __restrict__ h_bf,
                             int row0, int nrows){
  int total = nrows * 64;
  for (int idx = blockIdx.x * blockDim.x + threadIdx.x; idx < total; idx += gridDim.x * blockDim.x){
    int r = idx >> 6, c4 = (idx & 63) * 4;
    int t = x[row0 + r];
    float4 tv = *(const float4*)(tok + t * 256 + c4);
    float4 pv = *(const float4*)(pos + t * 256 + c4);
    ushort4 o;
    o.x = f2b(tv.x + pv.x); o.y = f2b(tv.y + pv.y);
    o.z = f2b(tv.z + pv.z); o.w = f2b(tv.w + pv.w);
    *(ushort4*)(h_bf + (size_t)r * 256 + c4) = o;
  }
}

// ---- MFMA fused attention: one block per sequence, 4 waves = 4 heads ----
__global__ __launch_bounds__(256)
void attn_mfma(const unsigned short* __restrict__ kqv, unsigned short* __restrict__ attn){
  __shared__ __align__(16) unsigned short VT[4][64 * 40];
  __shared__ __align__(16) unsigned short PH[4][32 * 40];
  const int ls = blockIdx.x;
  const int tid = threadIdx.x;
  const int hd = tid >> 6, lane = tid & 63;
  const int lm = lane & 15, lk = lane >> 4;

#pragma unroll
  for (int it = 0; it < 4; ++it){
    int idx = it * 256 + tid;
    int row = idx & 31, col = (idx >> 5) * 8;
    int hh = col >> 6, d = col & 63;
    union { uint4 v4; unsigned short s[8]; } u;
    u.v4 = *(const uint4*)(kqv + (size_t)(ls * 32 + row) * 768 + 512 + col);
#pragma unroll
    for (int j = 0; j < 8; ++j)
      VT[hh][(d + j) * 40 + row] = u.s[j];
  }
  __syncthreads();

  const unsigned short* Kg = kqv + (size_t)(ls * 32) * 768 + hd * 64;
  const unsigned short* Qg = Kg + 256;
  f32x4 sacc[2][2];
#pragma unroll
  for (int m = 0; m < 2; ++m)
#pragma unroll
    for (int n = 0; n < 2; ++n) sacc[m][n] = (f32x4){0.f, 0.f, 0.f, 0.f};
#pragma unroll
  for (int kk = 0; kk < 2; ++kk){
    bf16x8 a[2], b[2];
#pragma unroll
    for (int m = 0; m < 2; ++m)
      a[m] = *(const bf16x8*)(Kg + (size_t)(m * 16 + lm) * 768 + kk * 32 + lk * 8);
#pragma unroll
    for (int n = 0; n < 2; ++n)
      b[n] = *(const bf16x8*)(Qg + (size_t)(n * 16 + lm) * 768 + kk * 32 + lk * 8);
#pragma unroll
    for (int m = 0; m < 2; ++m)
#pragma unroll
      for (int n = 0; n < 2; ++n)
        sacc[m][n] = __builtin_amdgcn_mfma_f32_16x16x32_bf16(a[m], b[n], sacc[m][n], 0, 0, 0);
  }

#pragma unroll
  for (int m = 0; m < 2; ++m){
#pragma unroll
    for (int i = 0; i < 4; ++i){
      int t = m * 16 + lk * 4 + i;
      float v0 = sacc[m][0][i] * ATT_SCALE;
      float v1 = sacc[m][1][i] * ATT_SCALE;
      bool m0 = (lm <= t), m1 = (16 + lm <= t);
      float mx = fmaxf(m0 ? v0 : -1e30f, m1 ? v1 : -1e30f);
#pragma unroll
      for (int msk = 1; msk < 16; msk <<= 1) mx = fmaxf(mx, __shfl_xor(mx, msk, 64));
      float e0 = m0 ? expf(v0 - mx) : 0.f;
      float e1 = m1 ? expf(v1 - mx) : 0.f;
      float sm = e0 + e1;
#pragma unroll
      for (int msk = 1; msk < 16; msk <<= 1) sm += __shfl_xor(sm, msk, 64);
      float inv = 1.f / sm;
      PH[hd][t * 40 + lm]      = f2b(e0 * inv);
      PH[hd][t * 40 + 16 + lm] = f2b(e1 * inv);
    }
  }
  __syncthreads();

  f32x4 pacc[2][4];
  {
    bf16x8 a[2], b[4];
#pragma unroll
    for (int m = 0; m < 2; ++m)
      a[m] = *(const bf16x8*)&PH[hd][(m * 16 + lm) * 40 + lk * 8];
#pragma unroll
    for (int n = 0; n < 4; ++n)
      b[n] = *(const bf16x8*)&VT[hd][(n * 16 + lm) * 40 + lk * 8];
#pragma unroll
    for (int m = 0; m < 2; ++m)
#pragma unroll
      for (int n = 0; n < 4; ++n)
        pacc[m][n] = __builtin_amdgcn_mfma_f32_16x16x32_bf16(
            a[m], b[n], (f32x4){0.f, 0.f, 0.f, 0.f}, 0, 0, 0);
  }

  unsigned short* bounce = &VT[hd][0];
#pragma unroll
  for (int m = 0; m < 2; ++m)
#pragma unroll
    for (int n = 0; n < 4; ++n)
#pragma unroll
      for (int i = 0; i < 4; ++i)
        bounce[(m * 16 + lk * 4 + i) * 72 + n * 16 + lm] = f2b(pacc[m][n][i]);
  asm volatile("s_waitcnt lgkmcnt(0)" ::: "memory");
  const int er = lane >> 1, ec = (lane & 1) * 32;
  size_t gbase = (size_t)(ls * 32 + er) * 256 + hd * 64 + ec;
#pragma unroll
  for (int j = 0; j < 4; ++j)
    *(uint4*)(attn + gbase + j * 8) = *(const uint4*)&bounce[er * 72 + ec + j * 8];
}

// ---- fused logits (MFMA) + log-softmax + NLL ----
__global__ __launch_bounds__(256)
void logits_loss_mfma(const unsigned short* __restrict__ h_bf,
                      const unsigned short* __restrict__ lmWT,
                      const float* __restrict__ lmbp, const int* __restrict__ y,
                      float* __restrict__ out, float* __restrict__ partial,
                      int row0){
  __shared__ unsigned short As[64][136];
  __shared__ unsigned short Ws[80][136];
  __shared__ float redw[4];
  const int tid = threadIdx.x;
  const int rowBase = blockIdx.x * 64;
  const int w = tid >> 6, lane = tid & 63;
  const int lm = lane & 15, lk = lane >> 4;

  f32x4 acc[5];
#pragma unroll
  for (int n = 0; n < 5; ++n) acc[n] = (f32x4){0.f, 0.f, 0.f, 0.f};

  for (int kt = 0; kt < 256; kt += 128){
#pragma unroll
    for (int q = 0; q < 4; ++q){
      int idx = tid + 256 * q;
      int r = idx >> 4, k8 = (idx & 15) * 8;
      *(uint4*)&As[r][k8] = *(const uint4*)(h_bf + (size_t)(rowBase + r) * 256 + kt + k8);
    }
#pragma unroll
    for (int q = 0; q < 5; ++q){
      int idx = tid + 256 * q;
      int r = idx >> 4, k8 = (idx & 15) * 8;
      *(uint4*)&Ws[r][k8] = *(const uint4*)(lmWT + (size_t)r * 256 + kt + k8);
    }
    __syncthreads();
#pragma unroll
    for (int kc = 0; kc < 4; ++kc){
      bf16x8 a = *(const bf16x8*)&As[w * 16 + lm][kc * 32 + lk * 8];
#pragma unroll
      for (int n = 0; n < 5; ++n){
        bf16x8 bb = *(const bf16x8*)&Ws[n * 16 + lm][kc * 32 + lk * 8];
        acc[n] = __builtin_amdgcn_mfma_f32_16x16x32_bf16(a, bb, acc[n], 0, 0, 0);
      }
    }
    __syncthreads();
  }

#pragma unroll
  for (int n = 0; n < 5; ++n){
    int c = n * 16 + lm;
    float bv = lmbp[c];
#pragma unroll
    for (int i = 0; i < 4; ++i){
      acc[n][i] += bv;
      if (c < 65){
        int r = rowBase + w * 16 + lk * 4 + i;
        out[(size_t)(row0 + r) * 65 + c] = acc[n][i];
      }
    }
  }

  float nll = 0.f;
#pragma unroll
  for (int i = 0; i < 4; ++i){
    float mx = -1e30f;
#pragma unroll
    for (int n = 0; n < 5; ++n)
      if (n * 16 + lm < 65) mx = fmaxf(mx, acc[n][i]);
#pragma unroll
    for (int mask = 1; mask < 16; mask <<= 1) mx = fmaxf(mx, __shfl_xor(mx, mask, 64));
    float se = 0.f;
#pragma unroll
    for (int n = 0; n < 5; ++n)
      if (n * 16 + lm < 65) se += expf(acc[n][i] - mx);
#pragma unroll
    for (int mask = 1; mask < 16; mask <<= 1) se += __shfl_xor(se, mask, 64);
    float lse = mx + logf(se);
    int gr = rowBase + w * 16 + lk * 4 + i;
    int yv = y[row0 + gr];
    float ly = 0.f;
#pragma unroll
    for (int n = 0; n < 5; ++n)
      if (n * 16 + lm == yv) ly = acc[n][i];
#pragma unroll
    for (int mask = 1; mask < 16; mask <<= 1) ly += __shfl_xor(ly, mask, 64);
    nll += lse - ly;
  }
  if (lm != 0) nll = 0.f;
  nll += __shfl_xor(nll, 16, 64);
  nll += __shfl_xor(nll, 32, 64);
  if (lane == 0) redw[w] = nll;
  __syncthreads();
  if (tid == 0) partial[blockIdx.x] = redw[0] + redw[1] + redw[2] + redw[3];
}

__global__ __launch_bounds__(256)
void loss_red(const float* __restrict__ partial, int n, float* __restrict__ loss_sum){
  __shared__ float red[256];
  float s = 0.f;
  for (int i = threadIdx.x; i < n; i += 256) s += partial[i];
  red[threadIdx.x] = s;
  __syncthreads();
  for (int st = 128; st; st >>= 1){
    if (threadIdx.x < st) red[threadIdx.x] += red[threadIdx.x + st];
    __syncthreads();
  }
  if (threadIdx.x == 0) *loss_sum += red[0];
}

__global__ void loss_fin(const float* __restrict__ loss_sum, float* __restrict__ out){
  if (threadIdx.x == 0)
    out[(size_t)M_TOTAL * 65] = *loss_sum * (1.f / (float)M_TOTAL);
}

extern "C" void kernel_launch(void* const* d_in, const int* in_sizes, int n_in,
                              void* d_out, int out_size, void* d_ws, size_t ws_size,
                              hipStream_t stream) {
  const int*   x    = (const int*)  d_in[0];
  const int*   y    = (const int*)  d_in[1];
  const float* tok  = (const float*)d_in[2];
  const float* pos  = (const float*)d_in[3];
  const float* Wk   = (const float*)d_in[4];
  const float* Wq   = (const float*)d_in[5];
  const float* Wv   = (const float*)d_in[6];
  const float* Wp   = (const float*)d_in[7];
  const float* bp   = (const float*)d_in[8];
  const float* ln1g = (const float*)d_in[9];
  const float* ln1b = (const float*)d_in[10];
  const float* W1   = (const float*)d_in[11];
  const float* b1   = (const float*)d_in[12];
  const float* W2   = (const float*)d_in[13];
  const float* b2   = (const float*)d_in[14];
  const float* ln2g = (const float*)d_in[15];
  const float* ln2b = (const float*)d_in[16];
  const float* lmW  = (const float*)d_in[17];
  const float* lmb  = (const float*)d_in[18];
  float* out = (float*)d_out;

  // ws layout: loss_sum[64] | partial[1024] | lmWT+lmbp | bf16 weights | per-row buffers
  float* loss_sum = (float*)d_ws;
  float* partial  = loss_sum + 64;
  unsigned short* lmWT = (unsigned short*)(partial + 1024);      // [80][256]
  float* lmbp = (float*)(lmWT + 80 * 256);                       // [80]
  unsigned short* WrT = (unsigned short*)(lmbp + 80);            // [8][768][256]
  unsigned short* WpT = WrT + (size_t)8 * 768 * 256;             // [8][256][256]
  unsigned short* W1T = WpT + (size_t)8 * 256 * 256;             // [8][1024][256]
  unsigned short* W2T = W1T + (size_t)8 * 1024 * 256;            // [8][256][1024]
  unsigned short* bufs = W2T + (size_t)8 * 256 * 1024;
  size_t fixed = (size_t)(64 + 1024) * 4 + (size_t)80 * 256 * 2 + 80 * 4 +
                 ((size_t)8 * 768 * 256 + 8 * 256 * 256 + 8 * 1024 * 256 + 8 * 256 * 1024) * 2;
  // per-row (all bf16): kqv768 + h_bf256 + attn256 + ff1 1024
  const size_t per_row = (size_t)(768 + 256 + 256 + 1024) * 2;
  size_t avail = ws_size > fixed ? ws_size - fixed : 0;
  long rmax = (long)(avail / per_row) & ~255L;
  if (rmax < 256) rmax = 256;
  int R = (int)(rmax < (long)M_TOTAL ? rmax : (long)M_TOTAL);

  unsigned short* kqv_b  = bufs;                       // [R][768] bf16
  unsigned short* h_bf   = kqv_b  + (size_t)R * 768;   // [R][256] bf16 (residual stream)
  unsigned short* attn_b = h_bf   + (size_t)R * 256;   // [R][256] bf16
  unsigned short* ff1_b  = attn_b + (size_t)R * 256;   // [R][1024] bf16

  zero1<<<1, 64, 0, stream>>>(loss_sum);
  convert_qkv<<<CDIV(8 * 768 * 256, 256), 256, 0, stream>>>(Wk, Wq, Wv, WrT);
  convert_t<<<CDIV(8 * 256 * 256, 256), 256, 0, stream>>>(Wp, WpT, 256, 256, 8 * 256 * 256);
  convert_t<<<CDIV(8 * 1024 * 256, 256), 256, 0, stream>>>(W1, W1T, 1024, 256, 8 * 1024 * 256);
  convert_t<<<CDIV(8 * 256 * 1024, 256), 256, 0, stream>>>(W2, W2T, 256, 1024, 8 * 256 * 1024);
  convert_lmw<<<80, 256, 0, stream>>>(lmW, lmb, lmWT, lmbp);

  for (int row0 = 0; row0 < M_TOTAL; row0 += R){
    int nr = (M_TOTAL - row0) < R ? (M_TOTAL - row0) : R;
    int eg = CDIV(nr * 64, 256); if (eg > 4096) eg = 4096;
    embed_kernel<<<eg, 256, 0, stream>>>(x, tok, pos, h_bf, row0, nr);
    for (int i = 0; i < 8; ++i){
      gemm_bf<false><<<dim3(6, nr / 128), 256, 0, stream>>>(
          h_bf, WrT + (size_t)i * 768 * 256, nullptr, kqv_b, 768, 256);
      attn_mfma<<<nr / 32, 256, 0, stream>>>(kqv_b, attn_b);
      gemm_ln<<<nr / 128, 512, 0, stream>>>(
          attn_b, WpT + (size_t)i * 256 * 256, bp + i * 256, h_bf,
          ln1g + i * 256, ln1b + i * 256, 256);
      gemm_bf<true><<<dim3(8, nr / 128), 256, 0, stream>>>(
          h_bf, W1T + (size_t)i * 1024 * 256, b1 + i * 1024, ff1_b, 1024, 256);
      gemm_ln<<<nr / 128, 512, 0, stream>>>(
          ff1_b, W2T + (size_t)i * 256 * 1024, b2 + i * 256, h_bf,
          ln2g + i * 256, ln2b + i * 256, 1024);
    }
    logits_loss_mfma<<<nr / 64, 256, 0, stream>>>(h_bf, lmWT, lmbp, y, out, partial, row0);
    loss_red<<<1, 256, 0, stream>>>(partial, nr / 64, loss_sum);
  }
  loss_fin<<<1, 64, 0, stream>>>(loss_sum, out);
}